// Round 2
// baseline (8499.502 us; speedup 1.0000x reference)
//
#include <hip/hip_runtime.h>
#include <hip/hip_bf16.h>
#include <math.h>

// Problem dims
#define BATCH 256
#define SEQ   512
#define IN_D  512
#define HID   512
#define FOURH 2048
#define BS_ROWS (BATCH * SEQ)   // 131072

typedef __bf16 bf16x8 __attribute__((ext_vector_type(8)));
typedef float  f32x4  __attribute__((ext_vector_type(4)));

__device__ __forceinline__ float sigf(float x)  { return 1.0f / (1.0f + __expf(-x)); }
__device__ __forceinline__ float tanhf_(float x){ return 1.0f - 2.0f / (__expf(2.0f * x) + 1.0f); }

// ---------------------------------------------------------------------------
// Init: convert weights to bf16, fuse biases, zero h/c ping-pong bufs + barrier.
// ---------------------------------------------------------------------------
__global__ __launch_bounds__(256) void init_kernel(
    const float* __restrict__ W_all_w, const float* __restrict__ W_all_b,
    const float* __restrict__ U_all_w, const float* __restrict__ U_all_b,
    const float* __restrict__ W_d_w,
    __bf16* __restrict__ Wb, __bf16* __restrict__ Ub, __bf16* __restrict__ Db,
    float* __restrict__ bias_all,
    __bf16* __restrict__ h0, __bf16* __restrict__ c0,
    unsigned* __restrict__ bar)
{
    const int stride = gridDim.x * blockDim.x;
    const int tid0 = blockIdx.x * blockDim.x + threadIdx.x;

    const int nW = FOURH * HID;
    for (int i = tid0; i < nW; i += stride) {
        Wb[i] = (__bf16)W_all_w[i];
        Ub[i] = (__bf16)U_all_w[i];
    }
    const int nD = HID * HID;
    for (int i = tid0; i < nD; i += stride) Db[i] = (__bf16)W_d_w[i];
    for (int i = tid0; i < FOURH; i += stride) bias_all[i] = W_all_b[i] + U_all_b[i];
    const int nS = BATCH * HID;
    for (int i = tid0; i < nS; i += stride) {
        h0[i] = (__bf16)0.0f;
        c0[i] = (__bf16)0.0f;
    }
    for (int i = tid0; i < 8 * 64; i += stride) bar[i] = 0u;
}

// ---------------------------------------------------------------------------
// u_proj GEMM: up[B*S, 2048] = x[B*S, 512] @ U_all^T (bf16 out, no bias).
// 128x128 tile, 256 threads (4 waves, each 64x64), BK=64, K=512.
// Grid 16384 1-D with XCD-chunked remap so each XCD owns contiguous row panels.
// ---------------------------------------------------------------------------
__global__ __launch_bounds__(256) void uproj_gemm(
    const float* __restrict__ x, const __bf16* __restrict__ Ub,
    __bf16* __restrict__ up)
{
    const unsigned bid = blockIdx.x;
    const unsigned lg = (bid & 7) * 2048u + (bid >> 3);   // XCD-chunked, bijective
    const int cb = lg & 15;        // col tile (N=2048 / 128)
    const int rb = lg >> 4;        // row tile (131072 / 128)

    __shared__ __bf16 As[128][64];
    __shared__ __bf16 Bs[128][64];

    const int tid = threadIdx.x;
    const int wave = tid >> 6, lane = tid & 63;
    const int wm = wave >> 1, wn = wave & 1;
    const int lrow = lane & 15, kq = lane >> 4;
    const int sw = (lrow & 7) << 3;

    f32x4 acc[4][4];
    #pragma unroll
    for (int m = 0; m < 4; ++m)
        #pragma unroll
        for (int n = 0; n < 4; ++n) acc[m][n] = (f32x4){0.f, 0.f, 0.f, 0.f};

    const int srow = tid >> 1;
    const int skc  = (tid & 1) * 32;
    const int dsw  = (srow & 7) << 3;

    for (int kk = 0; kk < 512; kk += 64) {
        // stage A (f32 -> bf16)
        {
            const float* xs = x + (size_t)(rb * 128 + srow) * 512 + kk + skc;
            #pragma unroll
            for (int j = 0; j < 4; ++j) {
                float4 va = ((const float4*)xs)[2 * j];
                float4 vb = ((const float4*)xs)[2 * j + 1];
                bf16x8 pk;
                pk[0] = (__bf16)va.x; pk[1] = (__bf16)va.y;
                pk[2] = (__bf16)va.z; pk[3] = (__bf16)va.w;
                pk[4] = (__bf16)vb.x; pk[5] = (__bf16)vb.y;
                pk[6] = (__bf16)vb.z; pk[7] = (__bf16)vb.w;
                *(bf16x8*)&As[srow][(skc + j * 8) ^ dsw] = pk;
            }
            const __bf16* bsrc = Ub + (size_t)(cb * 128 + srow) * 512 + kk + skc;
            #pragma unroll
            for (int j = 0; j < 4; ++j)
                *(uint4*)&Bs[srow][(skc + j * 8) ^ dsw] = *(const uint4*)(bsrc + j * 8);
        }
        __syncthreads();

        #pragma unroll
        for (int k2 = 0; k2 < 2; ++k2) {
            const int ke = k2 * 32 + kq * 8;
            bf16x8 af[4], bfr[4];
            #pragma unroll
            for (int m = 0; m < 4; ++m)
                af[m] = *(const bf16x8*)&As[wm * 64 + m * 16 + lrow][ke ^ sw];
            #pragma unroll
            for (int n = 0; n < 4; ++n)
                bfr[n] = *(const bf16x8*)&Bs[wn * 64 + n * 16 + lrow][ke ^ sw];
            #pragma unroll
            for (int m = 0; m < 4; ++m)
                #pragma unroll
                for (int n = 0; n < 4; ++n)
                    acc[m][n] = __builtin_amdgcn_mfma_f32_16x16x32_bf16(af[m], bfr[n], acc[m][n], 0, 0, 0);
        }
        __syncthreads();
    }

    const int colL = lane & 15, r0 = (lane >> 4) * 4;
    const size_t orow0 = (size_t)rb * 128 + wm * 64;
    const int ocol0 = cb * 128 + wn * 64;
    #pragma unroll
    for (int m = 0; m < 4; ++m)
        #pragma unroll
        for (int n = 0; n < 4; ++n)
            #pragma unroll
            for (int i = 0; i < 4; ++i)
                up[(orow0 + m * 16 + r0 + i) * 2048 + ocol0 + n * 16 + colL] = (__bf16)acc[m][n][i];
}

// ---------------------------------------------------------------------------
// Persistent scan kernel. Grid 256 blocks x 320 threads (5 waves), 1 block/CU.
// Block (bg,hc): batch rows b0=bg*32..+31, hidden cols k0=hc*16..+15.
// Wave w in 0..3: gate group w (W_all rows w*512+k0+*); wave 4: W_d rows k0+*.
// Weights resident in LDS for all 512 steps. h/c ping-pong via global bf16.
// One inter-block (per-bg-group, 32 blocks) barrier per step.
// ---------------------------------------------------------------------------
__global__ __launch_bounds__(320) void scan_kernel(
    const __bf16* __restrict__ up,        // [B*S][2048]
    const float* __restrict__ timestamps, // [B][S]
    const __bf16* __restrict__ Wb,        // [2048][512]
    const __bf16* __restrict__ Db,        // [512][512]
    const float* __restrict__ bias_all,   // [2048]
    const float* __restrict__ Wd_b,       // [512]
    __bf16* __restrict__ h0buf, __bf16* __restrict__ h1buf,
    __bf16* __restrict__ c0buf, __bf16* __restrict__ c1buf,
    unsigned* __restrict__ bar,
    float* __restrict__ out)
{
    const int tid = threadIdx.x;
    const int bid = blockIdx.x;
    const int bg = bid & 7, hc = bid >> 3;
    const int b0 = bg * 32;
    const int k0 = hc * 16;
    const int wave = tid >> 6, lane = tid & 63;

    __shared__ __bf16 Bw[64][512];   // 64 KB: gate-group weights (w*16+r rows)
    __shared__ __bf16 Bd[16][512];   // 16 KB: W_d rows
    __shared__ __bf16 Ah[32][512];   // 32 KB: h tile
    __shared__ __bf16 Ac[32][512];   // 32 KB: c tile (front 10 KB aliased as gate exchange)
    __shared__ __bf16 Us[32][64];    //  4 KB: u slice
    __shared__ float  Cm[32][16];    //  2 KB: c master (f32, persistent)
    __shared__ float  BiasW[64];
    __shared__ float  BiasD[16];

    // ---- preload weights + biases, zero c master ----
    for (int ch = tid; ch < 4096; ch += 320) {
        const int row = ch >> 6, kc = (ch & 63) * 8;
        const int w = row >> 4, rr = row & 15;
        const __bf16* src = Wb + (size_t)(w * 512 + k0 + rr) * 512 + kc;
        *(uint4*)&Bw[row][kc ^ ((row & 7) << 3)] = *(const uint4*)src;
    }
    for (int ch = tid; ch < 1024; ch += 320) {
        const int row = ch >> 6, kc = (ch & 63) * 8;
        const __bf16* src = Db + (size_t)(k0 + row) * 512 + kc;
        *(uint4*)&Bd[row][kc ^ ((row & 7) << 3)] = *(const uint4*)src;
    }
    if (tid < 64) BiasW[tid] = bias_all[(tid >> 4) * 512 + k0 + (tid & 15)];
    else if (tid < 80) BiasD[tid - 64] = Wd_b[k0 + (tid - 64)];
    for (int e = tid; e < 512; e += 320) ((float*)Cm)[e] = 0.f;

    float* ex = (float*)&Ac[0][0];   // exchange: [5][32][16] f32 = 10 KB

    const int lrow = lane & 15, kq = lane >> 4;
    const int sw = (lrow & 7) << 3;

    __syncthreads();

    #pragma unroll 1
    for (int t = 0; t < SEQ; ++t) {
        const __bf16* hsrc = ((t & 1) ? h1buf : h0buf) + b0 * 512;
        const __bf16* csrc = ((t & 1) ? c1buf : c0buf) + b0 * 512;
        __bf16* hdst = ((t & 1) ? h0buf : h1buf) + b0 * 512;
        __bf16* cdst = ((t & 1) ? c0buf : c1buf) + b0 * 512;

        // ---- stage h, c, u ----
        for (int ch = tid; ch < 2048; ch += 320) {
            const int row = ch >> 6, kc = (ch & 63) * 8;
            const int d = row * 512 + (kc ^ ((row & 7) << 3));
            *(uint4*)(&Ah[0][0] + d) = *(const uint4*)(hsrc + row * 512 + kc);
            *(uint4*)(&Ac[0][0] + d) = *(const uint4*)(csrc + row * 512 + kc);
        }
        if (tid < 256) {
            const int row = tid >> 3, j = tid & 7;
            const __bf16* src = up + ((size_t)(b0 + row) * 512 + t) * 2048
                                   + (j >> 1) * 512 + k0 + (j & 1) * 8;
            *(uint4*)&Us[row][j * 8] = *(const uint4*)src;
        }
        __syncthreads();

        // ---- MFMA: 2 row-tiles x 1 col-tile per wave, K=512 ----
        f32x4 acc0 = {0.f, 0.f, 0.f, 0.f}, acc1 = {0.f, 0.f, 0.f, 0.f};
        const __bf16* Ab = (wave == 4) ? &Ac[0][0] : &Ah[0][0];
        const __bf16* Bb = (wave == 4) ? &Bd[0][0] : &Bw[wave * 16][0];
        #pragma unroll
        for (int kk = 0; kk < 512; kk += 32) {
            const int ke = (kk + kq * 8) ^ sw;
            bf16x8 a0 = *(const bf16x8*)(Ab + lrow * 512 + ke);
            bf16x8 a1 = *(const bf16x8*)(Ab + (16 + lrow) * 512 + ke);
            bf16x8 bb = *(const bf16x8*)(Bb + lrow * 512 + ke);
            acc0 = __builtin_amdgcn_mfma_f32_16x16x32_bf16(a0, bb, acc0, 0, 0, 0);
            acc1 = __builtin_amdgcn_mfma_f32_16x16x32_bf16(a1, bb, acc1, 0, 0, 0);
        }
        __syncthreads();

        // ---- epilogue: acc -> exchange (aliased over Ac front) ----
        {
            const int col = lane & 15, r0 = (lane >> 4) * 4;
            const float bias = (wave == 4) ? BiasD[col] : BiasW[wave * 16 + col];
            #pragma unroll
            for (int i = 0; i < 4; ++i) {
                ex[wave * 512 + (r0 + i) * 16 + col]      = acc0[i] + bias;
                ex[wave * 512 + (16 + r0 + i) * 16 + col] = acc1[i] + bias;
            }
        }
        __syncthreads();

        // ---- gate update (block-local) ----
        for (int e = tid; e < 512; e += 320) {
            const int r = e >> 4, k = e & 15;
            const float fo = ex[e]        + (float)Us[r][k];
            const float io = ex[512 + e]  + (float)Us[r][16 + k];
            const float oo = ex[1024 + e] + (float)Us[r][32 + k];
            const float ct = ex[1536 + e] + (float)Us[r][48 + k];
            const float dd = ex[2048 + e];
            const float c_old = Cm[r][k];
            const float tt = timestamps[(size_t)(b0 + r) * 512 + t];

            const float c_s1  = tanhf_(dd);
            const float c_adj = c_old - c_s1 + c_s1 * tt;
            const float f  = sigf(fo);
            const float ii = sigf(io);
            const float o  = sigf(oo);
            const float c_tmp = tanhf_(ct);
            const float c_new = f * c_adj + ii * c_tmp;
            const float h_new = o * tanhf_(c_new);

            Cm[r][k] = c_new;
            out[((size_t)(b0 + r) * 512 + t) * 512 + k0 + k] = o;
            hdst[r * 512 + k0 + k] = (__bf16)h_new;
            cdst[r * 512 + k0 + k] = (__bf16)c_new;
            if (t == SEQ - 1) {
                const size_t base = (size_t)BATCH * SEQ * HID;
                out[base + (size_t)(b0 + r) * 512 + k0 + k] = h_new;
                out[base + (size_t)BATCH * HID + (size_t)(b0 + r) * 512 + k0 + k] = c_new;
            }
        }

        // ---- per-group barrier (32 blocks sharing bg) ----
        if (t < SEQ - 1) {
            __syncthreads();   // drain all gate-phase global writes
            if (tid == 0) {
                __threadfence();
                atomicAdd(&bar[bg * 64], 1u);
                const unsigned tgt = 32u * (unsigned)(t + 1);
                while (__hip_atomic_load(&bar[bg * 64], __ATOMIC_ACQUIRE,
                                         __HIP_MEMORY_SCOPE_AGENT) < tgt)
                    __builtin_amdgcn_s_sleep(2);
            }
            __syncthreads();
        }
    }
}

// ---------------------------------------------------------------------------
extern "C" void kernel_launch(void* const* d_in, const int* in_sizes, int n_in,
                              void* d_out, int out_size, void* d_ws, size_t ws_size,
                              hipStream_t stream) {
    const float* inputs     = (const float*)d_in[0];
    const float* timestamps = (const float*)d_in[1];
    const float* W_all_w    = (const float*)d_in[2];
    const float* W_all_b    = (const float*)d_in[3];
    const float* U_all_w    = (const float*)d_in[4];
    const float* U_all_b    = (const float*)d_in[5];
    const float* W_d_w      = (const float*)d_in[6];
    const float* W_d_b      = (const float*)d_in[7];
    float* out = (float*)d_out;

    char* ws = (char*)d_ws;
    size_t off = 0;
    auto alloc = [&](size_t bytes) -> void* {
        void* p = ws + off;
        off += (bytes + 255) & ~(size_t)255;
        return p;
    };
    __bf16* Wb       = (__bf16*)alloc((size_t)FOURH * HID * 2);
    __bf16* Ub       = (__bf16*)alloc((size_t)FOURH * HID * 2);
    __bf16* Db       = (__bf16*)alloc((size_t)HID * HID * 2);
    float*  bias_all = (float*) alloc((size_t)FOURH * 4);
    __bf16* h0       = (__bf16*)alloc((size_t)BATCH * HID * 2);
    __bf16* h1       = (__bf16*)alloc((size_t)BATCH * HID * 2);
    __bf16* c0       = (__bf16*)alloc((size_t)BATCH * HID * 2);
    __bf16* c1       = (__bf16*)alloc((size_t)BATCH * HID * 2);
    unsigned* bar    = (unsigned*)alloc(8 * 64 * 4);
    __bf16* up       = (__bf16*)alloc((size_t)BS_ROWS * FOURH * 2);  // 512 MB

    hipLaunchKernelGGL(init_kernel, dim3(1024), dim3(256), 0, stream,
                       W_all_w, W_all_b, U_all_w, U_all_b, W_d_w,
                       Wb, Ub, Db, bias_all, h0, c0, bar);

    hipLaunchKernelGGL(uproj_gemm, dim3(16384), dim3(256), 0, stream,
                       inputs, Ub, up);

    void* sargs[] = {
        (void*)&up, (void*)&timestamps, (void*)&Wb, (void*)&Db,
        (void*)&bias_all, (void*)&W_d_b,
        (void*)&h0, (void*)&h1, (void*)&c0, (void*)&c1,
        (void*)&bar, (void*)&out
    };
    hipLaunchCooperativeKernel((const void*)scan_kernel, dim3(256), dim3(320),
                               sargs, 0, stream);
}